// Round 5
// baseline (4467.857 us; speedup 1.0000x reference)
//
#include <hip/hip_runtime.h>
#include <hip/hip_bf16.h>
#include <math.h>

// AoA Reader v3: MFMA GRU + reg-resident weights + raw barrier (no vmcnt drain) + gx prefetch.
// V=50000 E=384 H=256 B=32 D=1024 Q=64 C=10.
#define BATCH 32
#define DLEN 1024
#define QLEN 64
#define EMB 384
#define HID 256
#define G3 768   // 3*H
#define NCAND 10

typedef __attribute__((ext_vector_type(8))) short bf16x8;
typedef __attribute__((ext_vector_type(4))) float f32x4;
#define MFMA16 __builtin_amdgcn_mfma_f32_16x16x32_bf16

__device__ __forceinline__ float bf2f(ushort u) {
    union { float f; unsigned v; } x; x.v = ((unsigned)u) << 16; return x.f;
}
__device__ __forceinline__ ushort f2bf(float f) {
    union { float f; unsigned v; } x; x.f = f;
    unsigned r = x.v + 0x7FFF + ((x.v >> 16) & 1);
    return (ushort)(r >> 16);
}
__device__ __forceinline__ float sigf(float x) {
    return __builtin_amdgcn_rcpf(1.f + __expf(-x));
}
__device__ __forceinline__ float tanhf_(float x) {
    return 1.f - 2.f * __builtin_amdgcn_rcpf(1.f + __expf(2.f * x));
}

// ---------------- prep: w_hh (768x256 f32) -> bf16 MFMA B-fragment order ----------------
// layout: [dir][wave(8)][tile(6)][ks(8)][lane(64)][e(8)] bf16; per dir 196608 elems.
__global__ __launch_bounds__(256) void k_prep(const float* __restrict__ whf, const float* __restrict__ whb,
                                              ushort* __restrict__ wprep) {
    int idx = blockIdx.x * 256 + threadIdx.x;   // < 393216
    int dir = idx / 196608;
    int r = idx - dir * 196608;
    int wv = r / 24576;  int r2 = r - wv * 24576;
    int tile = r2 / 4096; int r3 = r2 - tile * 4096;
    int ks = r3 / 512;    int r4 = r3 - ks * 512;
    int lane = r4 >> 3;   int e = r4 & 7;
    int g = (tile >> 1) * 256 + wv * 32 + (tile & 1) * 16 + (lane & 15);
    int k = ks * 32 + (lane >> 4) * 8 + e;
    const float* w = dir ? whb : whf;
    wprep[idx] = f2bf(w[g * 256 + k]);
}

// ---------------- gx GEMM with gather (fp32 compute, bf16 out) ----------------
__global__ __launch_bounds__(256) void k_gx(const int* __restrict__ tokens,
                                            const float* __restrict__ emb,
                                            const float* __restrict__ w0, const float* __restrict__ bias0, ushort* __restrict__ out0,
                                            const float* __restrict__ w1, const float* __restrict__ bias1, ushort* __restrict__ out1) {
    __shared__ float As[16][68];
    __shared__ float Bs[16][68];
    const float* w   = blockIdx.z ? w1 : w0;
    const float* bia = blockIdx.z ? bias1 : bias0;
    ushort* out      = blockIdx.z ? out1 : out0;
    int tid = threadIdx.x;
    int n0 = blockIdx.x * 64;
    long m0 = (long)blockIdx.y * 64;
    int ml = tid >> 2, el = (tid & 3) << 2;
    long tok = tokens[m0 + ml];
    const float* arow = emb + tok * EMB;
    const float* brow = w + (long)(n0 + ml) * EMB;
    int ty = tid >> 4, tx = tid & 15;
    float acc[4][4] = {};
    for (int kt = 0; kt < EMB; kt += 16) {
        float4 av = *(const float4*)(arow + kt + el);
        float4 bv = *(const float4*)(brow + kt + el);
        __syncthreads();
        As[el + 0][ml] = av.x; As[el + 1][ml] = av.y; As[el + 2][ml] = av.z; As[el + 3][ml] = av.w;
        Bs[el + 0][ml] = bv.x; Bs[el + 1][ml] = bv.y; Bs[el + 2][ml] = bv.z; Bs[el + 3][ml] = bv.w;
        __syncthreads();
#pragma unroll
        for (int k = 0; k < 16; ++k) {
            float4 a4 = *(const float4*)&As[k][ty << 2];
            float4 b4 = *(const float4*)&Bs[k][tx << 2];
            float a[4] = {a4.x, a4.y, a4.z, a4.w};
            float bb[4] = {b4.x, b4.y, b4.z, b4.w};
#pragma unroll
            for (int i = 0; i < 4; ++i)
#pragma unroll
                for (int j = 0; j < 4; ++j)
                    acc[i][j] = fmaf(a[i], bb[j], acc[i][j]);
        }
    }
#pragma unroll
    for (int i = 0; i < 4; ++i) {
        long m = m0 + (ty << 2) + i;
        int n = n0 + (tx << 2);
        ushort4 pk;
        pk.x = f2bf(acc[i][0] + bia[n + 0]);
        pk.y = f2bf(acc[i][1] + bia[n + 1]);
        pk.z = f2bf(acc[i][2] + bia[n + 2]);
        pk.w = f2bf(acc[i][3] + bia[n + 3]);
        *(ushort4*)(out + m * G3 + n) = pk;
    }
}

// ---------------- MFMA GRU: grid 8 = (batch-half, dir, seq). 512 thr = 8 waves. ----------------
// Wave wv owns hidden units jw=wv*32..+31 (6 col-tiles; r/z/n j-aligned).
// Weights: tiles 0..4 in VGPRs (160 regs), tile 5 in LDS. h in LDS bf16, swizzled, dbuf.
// Raw s_barrier + lgkmcnt(0) per step (no vmcnt drain); gx prefetched one step ahead.
__global__ __launch_bounds__(512, 2) void k_gru5(
    const ushort* __restrict__ gxd_f, const ushort* __restrict__ gxd_b,
    const ushort* __restrict__ gxq_f, const ushort* __restrict__ gxq_b,
    const ushort* __restrict__ wprep,
    const float* __restrict__ bhh_f, const float* __restrict__ bhh_b,
    const int* __restrict__ dlens, const int* __restrict__ qlens,
    float* __restrict__ dosb, float* __restrict__ qosb)
{
    int wg = blockIdx.x;
    int bhalf = wg & 1;
    int dir = (wg >> 1) & 1;
    int seq = wg >> 2;                   // 0=doc, 1=query
    int T = seq ? QLEN : DLEN;
    const ushort* gx = seq ? (dir ? gxq_b : gxq_f) : (dir ? gxd_b : gxd_f);
    const float* bhh = dir ? bhh_b : bhh_f;
    const int* lens = seq ? qlens : dlens;
    float* outp = seq ? qosb : dosb;
    int boff = bhalf * 16;
    int diroff = dir * HID;

    int tid = threadIdx.x;
    int wv = tid >> 6;
    int lane = tid & 63;
    int l15 = lane & 15;
    int lhi = lane >> 4;                 // 0..3
    int jw = wv * 32;

    __shared__ ushort hbuf[2][16 * 256];         // 16 KB bf16 h, swizzled, dbuf
    __shared__ ushort Blds[8][8][512];           // 64 KB: tile 5 only

    // ---- resident weights: 5 tiles in VGPRs, 1 in LDS ----
    const ushort* wp = wprep + (size_t)dir * 196608;
    bf16x8 B[5][8];
#pragma unroll
    for (int tile = 0; tile < 5; ++tile)
#pragma unroll
        for (int ks = 0; ks < 8; ++ks)
            B[tile][ks] = *(const bf16x8*)(wp + ((((wv * 6 + tile) * 8 + ks) * 64 + lane) * 8));
#pragma unroll
    for (int ks = 0; ks < 8; ++ks) {
        bf16x8 t5 = *(const bf16x8*)(wp + ((((wv * 6 + 5) * 8 + ks) * 64 + lane) * 8));
        *(bf16x8*)&Blds[wv][ks][lane * 8] = t5;
    }

    float bhr0 = bhh[jw + l15],            bhr1 = bhh[jw + 16 + l15];
    float bhz0 = bhh[256 + jw + l15],      bhz1 = bhh[256 + jw + 16 + l15];
    float bhn0 = bhh[512 + jw + l15],      bhn1 = bhh[512 + jw + 16 + l15];
    int len[4];
#pragma unroll
    for (int i = 0; i < 4; ++i) len[i] = lens[boff + lhi * 4 + i];
    float hp[2][4] = {};

    for (int x = tid; x < 16 * 256; x += 512) hbuf[0][x] = 0;
    __syncthreads();   // full barrier once (Blds + hbuf init)

    int pos[4];
    ushort gxu[2][3][4];
    auto loadgx = [&](int t) {
#pragma unroll
        for (int i = 0; i < 4; ++i) {
            int p = t;
            if (dir) p = (t < len[i]) ? (len[i] - 1 - t) : t;
            pos[i] = p;
            const ushort* gr = gx + ((size_t)(boff + lhi * 4 + i) * T + p) * G3;
#pragma unroll
            for (int pp = 0; pp < 2; ++pp) {
                int j = jw + pp * 16 + l15;
                gxu[pp][0][i] = gr[j];
                gxu[pp][1][i] = gr[256 + j];
                gxu[pp][2][i] = gr[512 + j];
            }
        }
    };
    loadgx(0);   // prologue

    int cur = 0;
    for (int t = 0; t < T; ++t) {
        // ---- gh = h @ W^T via MFMA ----
        f32x4 acc0 = {0.f,0.f,0.f,0.f}, acc1 = acc0, acc2 = acc0, acc3 = acc0, acc4 = acc0, acc5 = acc0;
        const ushort* hb = hbuf[cur];
#pragma unroll
        for (int ks = 0; ks < 8; ++ks) {
            bf16x8 a = *(const bf16x8*)&hb[l15 * 256 + (((ks * 4 + lhi) ^ (l15 & 7)) * 8)];
            acc0 = MFMA16(a, B[0][ks], acc0, 0, 0, 0);
            acc1 = MFMA16(a, B[1][ks], acc1, 0, 0, 0);
            acc2 = MFMA16(a, B[2][ks], acc2, 0, 0, 0);
            acc3 = MFMA16(a, B[3][ks], acc3, 0, 0, 0);
            acc4 = MFMA16(a, B[4][ks], acc4, 0, 0, 0);
            bf16x8 b5 = *(const bf16x8*)&Blds[wv][ks][lane * 8];
            acc5 = MFMA16(a, b5, acc5, 0, 0, 0);
        }
        // ---- GRU update (C layout: col=l15 -> j, row=lhi*4+i -> batch) ----
        ushort* hn = hbuf[cur ^ 1];
#pragma unroll
        for (int p = 0; p < 2; ++p) {
            f32x4 ar = p ? acc1 : acc0;
            f32x4 az = p ? acc3 : acc2;
            f32x4 an = p ? acc5 : acc4;
            float bhr = p ? bhr1 : bhr0;
            float bhz = p ? bhz1 : bhz0;
            float bhn = p ? bhn1 : bhn0;
            int j = jw + p * 16 + l15;
#pragma unroll
            for (int i = 0; i < 4; ++i) {
                float rx = bf2f(gxu[p][0][i]);
                float zx = bf2f(gxu[p][1][i]);
                float nx = bf2f(gxu[p][2][i]);
                float r = sigf(rx + ar[i] + bhr);
                float z = sigf(zx + az[i] + bhz);
                float nn = tanhf_(nx + r * (an[i] + bhn));
                float h = (1.f - z) * nn + z * hp[p][i];
                hp[p][i] = h;
                int b = boff + lhi * 4 + i;
                outp[((size_t)b * T + pos[i]) * (2 * HID) + diroff + j] = h;
                int row = lhi * 4 + i;
                hn[row * 256 + (((j >> 3) ^ (row & 7)) * 8) + (j & 7)] = f2bf(h);
            }
        }
        // ---- prefetch gx for t+1 (lands during next barrier + MFMA phase) ----
        int tn = (t + 1 < T) ? (t + 1) : (T - 1);
        loadgx(tn);
        // ---- barrier WITHOUT vmcnt drain: only LDS writes must be visible ----
        asm volatile("s_waitcnt lgkmcnt(0)" ::: "memory");
        __builtin_amdgcn_sched_barrier(0);
        __builtin_amdgcn_s_barrier();
        __builtin_amdgcn_sched_barrier(0);
        cur ^= 1;
    }
}

// ---------------- M[b,d,q] = dos[b,d,:] . qos[b,q,:]  (K=512) ----------------
__global__ __launch_bounds__(256) void k_mgemm(const float* __restrict__ dos, const float* __restrict__ qos,
                                               float* __restrict__ Mm) {
    __shared__ float As[16][68];
    __shared__ float Bs[16][68];
    int tid = threadIdx.x;
    int b = blockIdx.y;
    long m0 = (long)blockIdx.x * 64;
    int ml = tid >> 2, el = (tid & 3) << 2;
    const float* arow = dos + ((long)b * DLEN + m0 + ml) * (2 * HID);
    const float* brow = qos + ((long)b * QLEN + ml) * (2 * HID);
    int ty = tid >> 4, tx = tid & 15;
    float acc[4][4] = {};
    for (int kt = 0; kt < 2 * HID; kt += 16) {
        float4 av = *(const float4*)(arow + kt + el);
        float4 bv = *(const float4*)(brow + kt + el);
        __syncthreads();
        As[el + 0][ml] = av.x; As[el + 1][ml] = av.y; As[el + 2][ml] = av.z; As[el + 3][ml] = av.w;
        Bs[el + 0][ml] = bv.x; Bs[el + 1][ml] = bv.y; Bs[el + 2][ml] = bv.z; Bs[el + 3][ml] = bv.w;
        __syncthreads();
#pragma unroll
        for (int k = 0; k < 16; ++k) {
            float4 a4 = *(const float4*)&As[k][ty << 2];
            float4 b4 = *(const float4*)&Bs[k][tx << 2];
            float a[4] = {a4.x, a4.y, a4.z, a4.w};
            float bb[4] = {b4.x, b4.y, b4.z, b4.w};
#pragma unroll
            for (int i = 0; i < 4; ++i)
#pragma unroll
                for (int j = 0; j < 4; ++j)
                    acc[i][j] = fmaf(a[i], bb[j], acc[i][j]);
        }
    }
#pragma unroll
    for (int i = 0; i < 4; ++i) {
        long m = m0 + (ty << 2) + i;
#pragma unroll
        for (int j = 0; j < 4; ++j) {
            int n = (tx << 2) + j;
            Mm[((long)b * DLEN + m) * QLEN + n] = acc[i][j];
        }
    }
}

// ---------------- avg_beta ----------------
__global__ __launch_bounds__(256) void k_avgbeta(const float* __restrict__ Mm, const float* __restrict__ dmask,
                                                 const float* __restrict__ qmask, const int* __restrict__ dlens,
                                                 float* __restrict__ avgb) {
    int b = blockIdx.x, tid = threadIdx.x;
    int lane = tid & 63, wid = tid >> 6;
    float qm = qmask[b * QLEN + lane];
    float acc = 0.f;
    for (int d = wid; d < DLEN; d += 4) {
        float x = Mm[((long)b * DLEN + d) * QLEN + lane];
        float mx = x;
#pragma unroll
        for (int o = 32; o; o >>= 1) mx = fmaxf(mx, __shfl_xor(mx, o));
        float e = expf(x - mx) * dmask[b * DLEN + d] * qm;
        float sm = e;
#pragma unroll
        for (int o = 32; o; o >>= 1) sm += __shfl_xor(sm, o);
        acc += e / (sm + 1e-12f);
    }
    __shared__ float red[4][QLEN];
    red[wid][lane] = acc;
    __syncthreads();
    if (tid < QLEN) {
        float tot = red[0][tid] + red[1][tid] + red[2][tid] + red[3][tid];
        avgb[b * QLEN + tid] = tot / (float)dlens[b];
    }
}

// ---------------- column stats over d ----------------
__global__ __launch_bounds__(256) void k_colstats(const float* __restrict__ Mm, const float* __restrict__ dmask,
                                                  float* __restrict__ mx, float* __restrict__ cs) {
    int b = blockIdx.x, tid = threadIdx.x;
    int q = tid & 63, dg = tid >> 6;
    float m = -INFINITY, ssum = 0.f;
    for (int d = dg; d < DLEN; d += 4) {
        float x = Mm[((long)b * DLEN + d) * QLEN + q];
        float dm = dmask[b * DLEN + d];
        float mn = fmaxf(m, x);
        ssum = ssum * expf(m - mn) + expf(x - mn) * dm;
        m = mn;
    }
    __shared__ float mS[4][QLEN], sS[4][QLEN];
    mS[dg][q] = m; sS[dg][q] = ssum;
    __syncthreads();
    if (tid < QLEN) {
        float M0 = fmaxf(fmaxf(mS[0][tid], mS[1][tid]), fmaxf(mS[2][tid], mS[3][tid]));
        float S = 0.f;
#pragma unroll
        for (int i = 0; i < 4; ++i) S += sS[i][tid] * expf(mS[i][tid] - M0);
        mx[b * QLEN + tid] = M0;
        cs[b * QLEN + tid] = S;
    }
}

// ---------------- s[b,d] ----------------
__global__ __launch_bounds__(256) void k_s(const float* __restrict__ Mm, const float* __restrict__ mxv, const float* __restrict__ cs,
                                           const float* __restrict__ avgb, const float* __restrict__ qmask, const float* __restrict__ dmask,
                                           float* __restrict__ s) {
    int b = blockIdx.y, tid = threadIdx.x;
    __shared__ float wq[QLEN], mxs[QLEN];
    if (tid < QLEN) {
        float part = cs[b * QLEN + tid];
        wq[tid] = (qmask[b * QLEN + tid] > 0.f) ? (avgb[b * QLEN + tid] / (part + 1e-12f)) : 0.f;
        mxs[tid] = mxv[b * QLEN + tid];
    }
    __syncthreads();
    long d = (long)blockIdx.x * 256 + tid;
    const float* row = Mm + ((long)b * DLEN + d) * QLEN;
    float acc = 0.f;
#pragma unroll
    for (int q = 0; q < QLEN; q += 4) {
        float4 v = *(const float4*)(row + q);
        acc += expf(v.x - mxs[q + 0]) * wq[q + 0];
        acc += expf(v.y - mxs[q + 1]) * wq[q + 1];
        acc += expf(v.z - mxs[q + 2]) * wq[q + 2];
        acc += expf(v.w - mxs[q + 3]) * wq[q + 3];
    }
    s[b * DLEN + d] = dmask[b * DLEN + d] * acc;
}

// ---------------- final ----------------
__global__ __launch_bounds__(256) void k_final(const float* __restrict__ s, const int* __restrict__ doc,
                                               const int* __restrict__ cand, const int* __restrict__ ans,
                                               float* __restrict__ out) {
    int b = blockIdx.x, tid = threadIdx.x;
    __shared__ int lc[NCAND];
    __shared__ int la;
    __shared__ float red[4][NCAND + 1];
    if (tid < NCAND) lc[tid] = cand[b * NCAND + tid];
    if (tid == NCAND) la = ans[b];
    __syncthreads();
    float accs[NCAND + 1] = {};
    for (int d = tid; d < DLEN; d += 256) {
        int tk = doc[b * DLEN + d];
        float sv = s[b * DLEN + d];
#pragma unroll
        for (int c = 0; c < NCAND; ++c)
            if (tk == lc[c]) accs[c] += sv;
        if (tk == la) accs[NCAND] += sv;
    }
    int lane = tid & 63, wid = tid >> 6;
#pragma unroll
    for (int i = 0; i <= NCAND; ++i) {
        float v = accs[i];
#pragma unroll
        for (int o = 32; o; o >>= 1) v += __shfl_xor(v, o);
        if (lane == 0) red[wid][i] = v;
    }
    __syncthreads();
    if (tid == 0) {
        float cp[NCAND + 1];
#pragma unroll
        for (int i = 0; i <= NCAND; ++i) cp[i] = red[0][i] + red[1][i] + red[2][i] + red[3][i];
        int loc = 0; float best = cp[0];
#pragma unroll
        for (int c = 1; c < NCAND; ++c) if (cp[c] > best) { best = cp[c]; loc = c; }
        out[b] = (float)lc[loc];
        out[BATCH + b] = (float)loc;
        out[2 * BATCH + b] = cp[NCAND];
    }
}

__global__ void k_zero_out(float* out, int n) {
    int i = blockIdx.x * 256 + threadIdx.x;
    if (i < n) out[i] = 0.f;
}

extern "C" void kernel_launch(void* const* d_in, const int* in_sizes, int n_in,
                              void* d_out, int out_size, void* d_ws, size_t ws_size,
                              hipStream_t stream) {
    const int*   docs_input   = (const int*)d_in[0];
    const int*   docs_len     = (const int*)d_in[1];
    const float* doc_mask     = (const float*)d_in[2];
    const int*   querys_input = (const int*)d_in[3];
    const int*   querys_len   = (const int*)d_in[4];
    const float* query_mask   = (const float*)d_in[5];
    const int*   candidates   = (const int*)d_in[6];
    const int*   answers      = (const int*)d_in[7];
    const float* embedding    = (const float*)d_in[8];
    const float* w_ih_f = (const float*)d_in[9];
    const float* w_hh_f = (const float*)d_in[10];
    const float* b_ih_f = (const float*)d_in[11];
    const float* b_hh_f = (const float*)d_in[12];
    const float* w_ih_b = (const float*)d_in[13];
    const float* w_hh_b = (const float*)d_in[14];
    const float* b_ih_b = (const float*)d_in[15];
    const float* b_hh_b = (const float*)d_in[16];

    char* ws = (char*)d_ws;
    size_t off = 0;
    auto alloc = [&](size_t bytes) { size_t o = off; off = (off + bytes + 255) & ~(size_t)255; return o; };
    ushort* wprep = (ushort*)(ws + alloc((size_t)2 * 196608 * 2));
    ushort* gxq_f = (ushort*)(ws + alloc((size_t)BATCH * QLEN * G3 * 2));
    ushort* gxq_b = (ushort*)(ws + alloc((size_t)BATCH * QLEN * G3 * 2));
    ushort* gxd_f = (ushort*)(ws + alloc((size_t)BATCH * DLEN * G3 * 2));
    ushort* gxd_b = (ushort*)(ws + alloc((size_t)BATCH * DLEN * G3 * 2));
    float* dosb  = (float*)(ws + alloc((size_t)BATCH * DLEN * 2 * HID * 4));
    float* qosb  = (float*)(ws + alloc((size_t)BATCH * QLEN * 2 * HID * 4));
    float* Mbuf  = (float*)(ws + alloc((size_t)BATCH * DLEN * QLEN * 4));
    float* avgb  = (float*)(ws + alloc((size_t)BATCH * QLEN * 4));
    float* mxb   = (float*)(ws + alloc((size_t)BATCH * QLEN * 4));
    float* csb   = (float*)(ws + alloc((size_t)BATCH * QLEN * 4));
    float* sbuf  = (float*)(ws + alloc((size_t)BATCH * DLEN * 4));

    if (ws_size < off) {
        k_zero_out<<<1, 256, 0, stream>>>((float*)d_out, out_size);
        return;
    }

    // weight fragments (bf16, MFMA B layout)
    k_prep<<<1536, 256, 0, stream>>>(w_hh_f, w_hh_b, wprep);

    // gx for queries and docs, both directions (bf16 out)
    k_gx<<<dim3(12, (BATCH * QLEN) / 64, 2), 256, 0, stream>>>(querys_input, embedding,
        w_ih_f, b_ih_f, gxq_f, w_ih_b, b_ih_b, gxq_b);
    k_gx<<<dim3(12, (BATCH * DLEN) / 64, 2), 256, 0, stream>>>(docs_input, embedding,
        w_ih_f, b_ih_f, gxd_f, w_ih_b, b_ih_b, gxd_b);

    // all four BiGRU scans (doc/query x fwd/bwd), batch split in halves of 16
    k_gru5<<<8, 512, 0, stream>>>(gxd_f, gxd_b, gxq_f, gxq_b, wprep,
                                  b_hh_f, b_hh_b, docs_len, querys_len, dosb, qosb);

    // attention-over-attention
    k_mgemm<<<dim3(DLEN / 64, BATCH), 256, 0, stream>>>(dosb, qosb, Mbuf);
    k_avgbeta<<<BATCH, 256, 0, stream>>>(Mbuf, doc_mask, query_mask, docs_len, avgb);
    k_colstats<<<BATCH, 256, 0, stream>>>(Mbuf, doc_mask, mxb, csb);
    k_s<<<dim3(DLEN / 256, BATCH), 256, 0, stream>>>(Mbuf, mxb, csb, avgb, query_mask, doc_mask, sbuf);
    k_final<<<BATCH, 256, 0, stream>>>(sbuf, docs_input, candidates, answers, (float*)d_out);
}

// Round 6
// 2950.719 us; speedup vs baseline: 1.5142x; 1.5142x over previous
//
#include <hip/hip_runtime.h>
#include <hip/hip_bf16.h>
#include <math.h>

// AoA Reader v4: MFMA GRU, forced 256-VGPR budget (waves_per_eu(2,2)),
// precomputed/immediate addressing (VALU diet), cvt_pk bf16 packing.
// V=50000 E=384 H=256 B=32 D=1024 Q=64 C=10.
#define BATCH 32
#define DLEN 1024
#define QLEN 64
#define EMB 384
#define HID 256
#define G3 768   // 3*H
#define NCAND 10

typedef __attribute__((ext_vector_type(8))) short bf16x8;
typedef __attribute__((ext_vector_type(4))) float f32x4;
#define MFMA16 __builtin_amdgcn_mfma_f32_16x16x32_bf16

__device__ __forceinline__ float bf2f(ushort u) {
    union { float f; unsigned v; } x; x.v = ((unsigned)u) << 16; return x.f;
}
__device__ __forceinline__ ushort f2bf(float f) {
    union { float f; unsigned v; } x; x.f = f;
    unsigned r = x.v + 0x7FFF + ((x.v >> 16) & 1);
    return (ushort)(r >> 16);
}
__device__ __forceinline__ float sigf(float x) {
    return __builtin_amdgcn_rcpf(1.f + __expf(-x));
}
__device__ __forceinline__ float tanhf_(float x) {
    return 1.f - 2.f * __builtin_amdgcn_rcpf(1.f + __expf(2.f * x));
}

// ---------------- prep: w_hh (768x256 f32) -> bf16 MFMA B-fragment order ----------------
// layout: [dir][wave(8)][tile(6)][ks(8)][lane(64)][e(8)] bf16; per dir 196608 elems.
__global__ __launch_bounds__(256) void k_prep(const float* __restrict__ whf, const float* __restrict__ whb,
                                              ushort* __restrict__ wprep) {
    int idx = blockIdx.x * 256 + threadIdx.x;   // < 393216
    int dir = idx / 196608;
    int r = idx - dir * 196608;
    int wv = r / 24576;  int r2 = r - wv * 24576;
    int tile = r2 / 4096; int r3 = r2 - tile * 4096;
    int ks = r3 / 512;    int r4 = r3 - ks * 512;
    int lane = r4 >> 3;   int e = r4 & 7;
    int g = (tile >> 1) * 256 + wv * 32 + (tile & 1) * 16 + (lane & 15);
    int k = ks * 32 + (lane >> 4) * 8 + e;
    const float* w = dir ? whb : whf;
    wprep[idx] = f2bf(w[g * 256 + k]);
}

// ---------------- gx GEMM with gather (fp32 compute, bf16 out) ----------------
__global__ __launch_bounds__(256) void k_gx(const int* __restrict__ tokens,
                                            const float* __restrict__ emb,
                                            const float* __restrict__ w0, const float* __restrict__ bias0, ushort* __restrict__ out0,
                                            const float* __restrict__ w1, const float* __restrict__ bias1, ushort* __restrict__ out1) {
    __shared__ float As[16][68];
    __shared__ float Bs[16][68];
    const float* w   = blockIdx.z ? w1 : w0;
    const float* bia = blockIdx.z ? bias1 : bias0;
    ushort* out      = blockIdx.z ? out1 : out0;
    int tid = threadIdx.x;
    int n0 = blockIdx.x * 64;
    long m0 = (long)blockIdx.y * 64;
    int ml = tid >> 2, el = (tid & 3) << 2;
    long tok = tokens[m0 + ml];
    const float* arow = emb + tok * EMB;
    const float* brow = w + (long)(n0 + ml) * EMB;
    int ty = tid >> 4, tx = tid & 15;
    float acc[4][4] = {};
    for (int kt = 0; kt < EMB; kt += 16) {
        float4 av = *(const float4*)(arow + kt + el);
        float4 bv = *(const float4*)(brow + kt + el);
        __syncthreads();
        As[el + 0][ml] = av.x; As[el + 1][ml] = av.y; As[el + 2][ml] = av.z; As[el + 3][ml] = av.w;
        Bs[el + 0][ml] = bv.x; Bs[el + 1][ml] = bv.y; Bs[el + 2][ml] = bv.z; Bs[el + 3][ml] = bv.w;
        __syncthreads();
#pragma unroll
        for (int k = 0; k < 16; ++k) {
            float4 a4 = *(const float4*)&As[k][ty << 2];
            float4 b4 = *(const float4*)&Bs[k][tx << 2];
            float a[4] = {a4.x, a4.y, a4.z, a4.w};
            float bb[4] = {b4.x, b4.y, b4.z, b4.w};
#pragma unroll
            for (int i = 0; i < 4; ++i)
#pragma unroll
                for (int j = 0; j < 4; ++j)
                    acc[i][j] = fmaf(a[i], bb[j], acc[i][j]);
        }
    }
#pragma unroll
    for (int i = 0; i < 4; ++i) {
        long m = m0 + (ty << 2) + i;
        int n = n0 + (tx << 2);
        ushort4 pk;
        pk.x = f2bf(acc[i][0] + bia[n + 0]);
        pk.y = f2bf(acc[i][1] + bia[n + 1]);
        pk.z = f2bf(acc[i][2] + bia[n + 2]);
        pk.w = f2bf(acc[i][3] + bia[n + 3]);
        *(ushort4*)(out + m * G3 + n) = pk;
    }
}

// ---------------- MFMA GRU: grid 8 = (batch-half, dir, seq). 512 thr = 8 waves. ----------------
// 4 B-tiles in VGPRs (128 regs, real this time), 2 in LDS. All LDS/global addressing
// precomputed per-lane; step double-buffer via 2x unroll with static buffer index.
__global__ __attribute__((amdgpu_flat_work_group_size(512, 512), amdgpu_waves_per_eu(2, 2)))
void k_gru5(
    const ushort* __restrict__ gxd_f, const ushort* __restrict__ gxd_b,
    const ushort* __restrict__ gxq_f, const ushort* __restrict__ gxq_b,
    const ushort* __restrict__ wprep,
    const float* __restrict__ bhh_f, const float* __restrict__ bhh_b,
    const int* __restrict__ dlens, const int* __restrict__ qlens,
    float* __restrict__ dosb, float* __restrict__ qosb)
{
    int wg = blockIdx.x;
    int bhalf = wg & 1;
    int dir = (wg >> 1) & 1;
    int seq = wg >> 2;                   // 0=doc, 1=query
    int T = seq ? QLEN : DLEN;
    const ushort* gx = seq ? (dir ? gxq_b : gxq_f) : (dir ? gxd_b : gxd_f);
    const float* bhh = dir ? bhh_b : bhh_f;
    const int* lens = seq ? qlens : dlens;
    float* outbase = (seq ? qosb : dosb) + dir * HID;   // uniform base
    int boff = bhalf * 16;

    int tid = threadIdx.x;
    int wv = tid >> 6;
    int lane = tid & 63;
    int l15 = lane & 15;
    int lhi = lane >> 4;                 // 0..3
    int jw = wv * 32;

    __shared__ ushort hbuf[2][4096];             // 16 KB bf16 h, swizzled, dbuf
    __shared__ ushort Blds[8][2][8][512];        // 128 KB: tiles 4,5 per wave

    // ---- resident weights: tiles 0..3 in VGPRs, tiles 4,5 in LDS ----
    const ushort* wp = wprep + (size_t)dir * 196608;
    bf16x8 B0[8], B1[8], B2[8], B3[8];
#pragma unroll
    for (int ks = 0; ks < 8; ++ks) {
        B0[ks] = *(const bf16x8*)(wp + ((((wv * 6 + 0) * 8 + ks) * 64 + lane) * 8));
        B1[ks] = *(const bf16x8*)(wp + ((((wv * 6 + 1) * 8 + ks) * 64 + lane) * 8));
        B2[ks] = *(const bf16x8*)(wp + ((((wv * 6 + 2) * 8 + ks) * 64 + lane) * 8));
        B3[ks] = *(const bf16x8*)(wp + ((((wv * 6 + 3) * 8 + ks) * 64 + lane) * 8));
    }
#pragma unroll
    for (int tt = 0; tt < 2; ++tt)
#pragma unroll
        for (int ks = 0; ks < 8; ++ks) {
            bf16x8 t5 = *(const bf16x8*)(wp + ((((wv * 6 + 4 + tt) * 8 + ks) * 64 + lane) * 8));
            *(bf16x8*)((char*)&Blds[0][0][0][0] + wv * 16384 + tt * 8192 + ks * 1024 + lane * 16) = t5;
        }

    float bhr0 = bhh[jw + l15],            bhr1 = bhh[jw + 16 + l15];
    float bhz0 = bhh[256 + jw + l15],      bhz1 = bhh[256 + jw + 16 + l15];
    float bhn0 = bhh[512 + jw + l15],      bhn1 = bhh[512 + jw + 16 + l15];
    int len[4];
#pragma unroll
    for (int i = 0; i < 4; ++i) len[i] = lens[boff + lhi * 4 + i];
    float hp[2][4] = {};

    // ---- precomputed static addresses (t-invariant) ----
    int a_addr[8];
#pragma unroll
    for (int ks = 0; ks < 8; ++ks)
        a_addr[ks] = l15 * 512 + (((ks * 4 + lhi) ^ (l15 & 7)) * 16);
    int wofs[2][4];
#pragma unroll
    for (int p = 0; p < 2; ++p)
#pragma unroll
        for (int i = 0; i < 4; ++i) {
            int row = lhi * 4 + i, j = jw + p * 16 + l15;
            wofs[p][i] = (row * 256 + (((j >> 3) ^ (row & 7)) * 8) + (j & 7)) * 2;
        }
    int blbase = wv * 16384 + lane * 16;
    int lbg[4], lbo[4];                          // 32-bit lane base byte-offsets
#pragma unroll
    for (int i = 0; i < 4; ++i) {
        int b = boff + lhi * 4 + i;
        lbg[i] = b * T * (G3 * 2) + (jw + l15) * 2;
        lbo[i] = b * T * (512 * 4) + (jw + l15) * 4;
    }

    for (int x = tid; x < 4096; x += 512) hbuf[0][x] = 0;
    __syncthreads();

#define GSTEP(RB, WB, TT)                                                         \
    {                                                                             \
        int voffg[4], voffo[4];                                                   \
        _Pragma("unroll")                                                         \
        for (int i = 0; i < 4; ++i) {                                             \
            int p_ = (TT);                                                        \
            if (dir) p_ = ((TT) < len[i]) ? (len[i] - 1 - (TT)) : (TT);           \
            voffg[i] = lbg[i] + p_ * 1536;                                        \
            voffo[i] = lbo[i] + p_ * 2048;                                        \
        }                                                                         \
        ushort gxu[2][3][4];                                                      \
        _Pragma("unroll")                                                         \
        for (int i = 0; i < 4; ++i) {                                             \
            const ushort* g = (const ushort*)((const char*)gx + voffg[i]);        \
            gxu[0][0][i] = g[0];   gxu[1][0][i] = g[16];                          \
            gxu[0][1][i] = g[256]; gxu[1][1][i] = g[272];                         \
            gxu[0][2][i] = g[512]; gxu[1][2][i] = g[528];                         \
        }                                                                         \
        f32x4 acc0 = {0.f,0.f,0.f,0.f}, acc1 = acc0, acc2 = acc0,                 \
              acc3 = acc0, acc4 = acc0, acc5 = acc0;                              \
        _Pragma("unroll")                                                         \
        for (int ks = 0; ks < 8; ++ks) {                                          \
            bf16x8 a = *(const bf16x8*)((const char*)&hbuf[RB][0] + a_addr[ks]);  \
            acc0 = MFMA16(a, B0[ks], acc0, 0, 0, 0);                              \
            acc1 = MFMA16(a, B1[ks], acc1, 0, 0, 0);                              \
            acc2 = MFMA16(a, B2[ks], acc2, 0, 0, 0);                              \
            acc3 = MFMA16(a, B3[ks], acc3, 0, 0, 0);                              \
            bf16x8 b4 = *(const bf16x8*)((const char*)&Blds[0][0][0][0] + blbase + ks * 1024);        \
            bf16x8 b5 = *(const bf16x8*)((const char*)&Blds[0][0][0][0] + blbase + 8192 + ks * 1024); \
            acc4 = MFMA16(a, b4, acc4, 0, 0, 0);                                  \
            acc5 = MFMA16(a, b5, acc5, 0, 0, 0);                                  \
        }                                                                         \
        _Pragma("unroll")                                                         \
        for (int i = 0; i < 4; ++i) {                                             \
            float h2[2];                                                          \
            _Pragma("unroll")                                                     \
            for (int p = 0; p < 2; ++p) {                                         \
                float ar = p ? acc1[i] : acc0[i];                                 \
                float az = p ? acc3[i] : acc2[i];                                 \
                float an = p ? acc5[i] : acc4[i];                                 \
                float rx = bf2f(gxu[p][0][i]);                                    \
                float zx = bf2f(gxu[p][1][i]);                                    \
                float nx = bf2f(gxu[p][2][i]);                                    \
                float r = sigf(rx + ar + (p ? bhr1 : bhr0));                      \
                float z = sigf(zx + az + (p ? bhz1 : bhz0));                      \
                float nn = tanhf_(nx + r * (an + (p ? bhn1 : bhn0)));             \
                float h = (1.f - z) * nn + z * hp[p][i];                          \
                hp[p][i] = h;                                                     \
                h2[p] = h;                                                        \
                float* o = (float*)((char*)outbase + voffo[i]);                   \
                o[p * 16] = h;                                                    \
            }                                                                     \
            unsigned pk;                                                          \
            asm("v_cvt_pk_bf16_f32 %0, %1, %2" : "=v"(pk) : "v"(h2[0]), "v"(h2[1])); \
            *(ushort*)((char*)&hbuf[WB][0] + wofs[0][i]) = (ushort)(pk & 0xffffu); \
            *(ushort*)((char*)&hbuf[WB][0] + wofs[1][i]) = (ushort)(pk >> 16);    \
        }                                                                         \
        __syncthreads();                                                          \
    }

    for (int t = 0; t < T; t += 2) {
        GSTEP(0, 1, t)
        GSTEP(1, 0, t + 1)
    }
#undef GSTEP
}

// ---------------- M[b,d,q] = dos[b,d,:] . qos[b,q,:]  (K=512) ----------------
__global__ __launch_bounds__(256) void k_mgemm(const float* __restrict__ dos, const float* __restrict__ qos,
                                               float* __restrict__ Mm) {
    __shared__ float As[16][68];
    __shared__ float Bs[16][68];
    int tid = threadIdx.x;
    int b = blockIdx.y;
    long m0 = (long)blockIdx.x * 64;
    int ml = tid >> 2, el = (tid & 3) << 2;
    const float* arow = dos + ((long)b * DLEN + m0 + ml) * (2 * HID);
    const float* brow = qos + ((long)b * QLEN + ml) * (2 * HID);
    int ty = tid >> 4, tx = tid & 15;
    float acc[4][4] = {};
    for (int kt = 0; kt < 2 * HID; kt += 16) {
        float4 av = *(const float4*)(arow + kt + el);
        float4 bv = *(const float4*)(brow + kt + el);
        __syncthreads();
        As[el + 0][ml] = av.x; As[el + 1][ml] = av.y; As[el + 2][ml] = av.z; As[el + 3][ml] = av.w;
        Bs[el + 0][ml] = bv.x; Bs[el + 1][ml] = bv.y; Bs[el + 2][ml] = bv.z; Bs[el + 3][ml] = bv.w;
        __syncthreads();
#pragma unroll
        for (int k = 0; k < 16; ++k) {
            float4 a4 = *(const float4*)&As[k][ty << 2];
            float4 b4 = *(const float4*)&Bs[k][tx << 2];
            float a[4] = {a4.x, a4.y, a4.z, a4.w};
            float bb[4] = {b4.x, b4.y, b4.z, b4.w};
#pragma unroll
            for (int i = 0; i < 4; ++i)
#pragma unroll
                for (int j = 0; j < 4; ++j)
                    acc[i][j] = fmaf(a[i], bb[j], acc[i][j]);
        }
    }
#pragma unroll
    for (int i = 0; i < 4; ++i) {
        long m = m0 + (ty << 2) + i;
#pragma unroll
        for (int j = 0; j < 4; ++j) {
            int n = (tx << 2) + j;
            Mm[((long)b * DLEN + m) * QLEN + n] = acc[i][j];
        }
    }
}

// ---------------- avg_beta ----------------
__global__ __launch_bounds__(256) void k_avgbeta(const float* __restrict__ Mm, const float* __restrict__ dmask,
                                                 const float* __restrict__ qmask, const int* __restrict__ dlens,
                                                 float* __restrict__ avgb) {
    int b = blockIdx.x, tid = threadIdx.x;
    int lane = tid & 63, wid = tid >> 6;
    float qm = qmask[b * QLEN + lane];
    float acc = 0.f;
    for (int d = wid; d < DLEN; d += 4) {
        float x = Mm[((long)b * DLEN + d) * QLEN + lane];
        float mx = x;
#pragma unroll
        for (int o = 32; o; o >>= 1) mx = fmaxf(mx, __shfl_xor(mx, o));
        float e = expf(x - mx) * dmask[b * DLEN + d] * qm;
        float sm = e;
#pragma unroll
        for (int o = 32; o; o >>= 1) sm += __shfl_xor(sm, o);
        acc += e / (sm + 1e-12f);
    }
    __shared__ float red[4][QLEN];
    red[wid][lane] = acc;
    __syncthreads();
    if (tid < QLEN) {
        float tot = red[0][tid] + red[1][tid] + red[2][tid] + red[3][tid];
        avgb[b * QLEN + tid] = tot / (float)dlens[b];
    }
}

// ---------------- column stats over d ----------------
__global__ __launch_bounds__(256) void k_colstats(const float* __restrict__ Mm, const float* __restrict__ dmask,
                                                  float* __restrict__ mx, float* __restrict__ cs) {
    int b = blockIdx.x, tid = threadIdx.x;
    int q = tid & 63, dg = tid >> 6;
    float m = -INFINITY, ssum = 0.f;
    for (int d = dg; d < DLEN; d += 4) {
        float x = Mm[((long)b * DLEN + d) * QLEN + q];
        float dm = dmask[b * DLEN + d];
        float mn = fmaxf(m, x);
        ssum = ssum * expf(m - mn) + expf(x - mn) * dm;
        m = mn;
    }
    __shared__ float mS[4][QLEN], sS[4][QLEN];
    mS[dg][q] = m; sS[dg][q] = ssum;
    __syncthreads();
    if (tid < QLEN) {
        float M0 = fmaxf(fmaxf(mS[0][tid], mS[1][tid]), fmaxf(mS[2][tid], mS[3][tid]));
        float S = 0.f;
#pragma unroll
        for (int i = 0; i < 4; ++i) S += sS[i][tid] * expf(mS[i][tid] - M0);
        mx[b * QLEN + tid] = M0;
        cs[b * QLEN + tid] = S;
    }
}

// ---------------- s[b,d] ----------------
__global__ __launch_bounds__(256) void k_s(const float* __restrict__ Mm, const float* __restrict__ mxv, const float* __restrict__ cs,
                                           const float* __restrict__ avgb, const float* __restrict__ qmask, const float* __restrict__ dmask,
                                           float* __restrict__ s) {
    int b = blockIdx.y, tid = threadIdx.x;
    __shared__ float wq[QLEN], mxs[QLEN];
    if (tid < QLEN) {
        float part = cs[b * QLEN + tid];
        wq[tid] = (qmask[b * QLEN + tid] > 0.f) ? (avgb[b * QLEN + tid] / (part + 1e-12f)) : 0.f;
        mxs[tid] = mxv[b * QLEN + tid];
    }
    __syncthreads();
    long d = (long)blockIdx.x * 256 + tid;
    const float* row = Mm + ((long)b * DLEN + d) * QLEN;
    float acc = 0.f;
#pragma unroll
    for (int q = 0; q < QLEN; q += 4) {
        float4 v = *(const float4*)(row + q);
        acc += expf(v.x - mxs[q + 0]) * wq[q + 0];
        acc += expf(v.y - mxs[q + 1]) * wq[q + 1];
        acc += expf(v.z - mxs[q + 2]) * wq[q + 2];
        acc += expf(v.w - mxs[q + 3]) * wq[q + 3];
    }
    s[b * DLEN + d] = dmask[b * DLEN + d] * acc;
}

// ---------------- final ----------------
__global__ __launch_bounds__(256) void k_final(const float* __restrict__ s, const int* __restrict__ doc,
                                               const int* __restrict__ cand, const int* __restrict__ ans,
                                               float* __restrict__ out) {
    int b = blockIdx.x, tid = threadIdx.x;
    __shared__ int lc[NCAND];
    __shared__ int la;
    __shared__ float red[4][NCAND + 1];
    if (tid < NCAND) lc[tid] = cand[b * NCAND + tid];
    if (tid == NCAND) la = ans[b];
    __syncthreads();
    float accs[NCAND + 1] = {};
    for (int d = tid; d < DLEN; d += 256) {
        int tk = doc[b * DLEN + d];
        float sv = s[b * DLEN + d];
#pragma unroll
        for (int c = 0; c < NCAND; ++c)
            if (tk == lc[c]) accs[c] += sv;
        if (tk == la) accs[NCAND] += sv;
    }
    int lane = tid & 63, wid = tid >> 6;
#pragma unroll
    for (int i = 0; i <= NCAND; ++i) {
        float v = accs[i];
#pragma unroll
        for (int o = 32; o; o >>= 1) v += __shfl_xor(v, o);
        if (lane == 0) red[wid][i] = v;
    }
    __syncthreads();
    if (tid == 0) {
        float cp[NCAND + 1];
#pragma unroll
        for (int i = 0; i <= NCAND; ++i) cp[i] = red[0][i] + red[1][i] + red[2][i] + red[3][i];
        int loc = 0; float best = cp[0];
#pragma unroll
        for (int c = 1; c < NCAND; ++c) if (cp[c] > best) { best = cp[c]; loc = c; }
        out[b] = (float)lc[loc];
        out[BATCH + b] = (float)loc;
        out[2 * BATCH + b] = cp[NCAND];
    }
}

__global__ void k_zero_out(float* out, int n) {
    int i = blockIdx.x * 256 + threadIdx.x;
    if (i < n) out[i] = 0.f;
}

extern "C" void kernel_launch(void* const* d_in, const int* in_sizes, int n_in,
                              void* d_out, int out_size, void* d_ws, size_t ws_size,
                              hipStream_t stream) {
    const int*   docs_input   = (const int*)d_in[0];
    const int*   docs_len     = (const int*)d_in[1];
    const float* doc_mask     = (const float*)d_in[2];
    const int*   querys_input = (const int*)d_in[3];
    const int*   querys_len   = (const int*)d_in[4];
    const float* query_mask   = (const float*)d_in[5];
    const int*   candidates   = (const int*)d_in[6];
    const int*   answers      = (const int*)d_in[7];
    const float* embedding    = (const float*)d_in[8];
    const float* w_ih_f = (const float*)d_in[9];
    const float* w_hh_f = (const float*)d_in[10];
    const float* b_ih_f = (const float*)d_in[11];
    const float* b_hh_f = (const float*)d_in[12];
    const float* w_ih_b = (const float*)d_in[13];
    const float* w_hh_b = (const float*)d_in[14];
    const float* b_ih_b = (const float*)d_in[15];
    const float* b_hh_b = (const float*)d_in[16];

    char* ws = (char*)d_ws;
    size_t off = 0;
    auto alloc = [&](size_t bytes) { size_t o = off; off = (off + bytes + 255) & ~(size_t)255; return o; };
    ushort* wprep = (ushort*)(ws + alloc((size_t)2 * 196608 * 2));
    ushort* gxq_f = (ushort*)(ws + alloc((size_t)BATCH * QLEN * G3 * 2));
    ushort* gxq_b = (ushort*)(ws + alloc((size_t)BATCH * QLEN * G3 * 2));
    ushort* gxd_f = (ushort*)(ws + alloc((size_t)BATCH * DLEN * G3 * 2));
    ushort* gxd_b = (ushort*)(ws + alloc((size_t)BATCH * DLEN * G3 * 2));
    float* dosb  = (float*)(ws + alloc((size_t)BATCH * DLEN * 2 * HID * 4));
    float* qosb  = (float*)(ws + alloc((size_t)BATCH * QLEN * 2 * HID * 4));
    float* Mbuf  = (float*)(ws + alloc((size_t)BATCH * DLEN * QLEN * 4));
    float* avgb  = (float*)(ws + alloc((size_t)BATCH * QLEN * 4));
    float* mxb   = (float*)(ws + alloc((size_t)BATCH * QLEN * 4));
    float* csb   = (float*)(ws + alloc((size_t)BATCH * QLEN * 4));
    float* sbuf  = (float*)(ws + alloc((size_t)BATCH * DLEN * 4));

    if (ws_size < off) {
        k_zero_out<<<1, 256, 0, stream>>>((float*)d_out, out_size);
        return;
    }

    // weight fragments (bf16, MFMA B layout)
    k_prep<<<1536, 256, 0, stream>>>(w_hh_f, w_hh_b, wprep);

    // gx for queries and docs, both directions (bf16 out)
    k_gx<<<dim3(12, (BATCH * QLEN) / 64, 2), 256, 0, stream>>>(querys_input, embedding,
        w_ih_f, b_ih_f, gxq_f, w_ih_b, b_ih_b, gxq_b);
    k_gx<<<dim3(12, (BATCH * DLEN) / 64, 2), 256, 0, stream>>>(docs_input, embedding,
        w_ih_f, b_ih_f, gxd_f, w_ih_b, b_ih_b, gxd_b);

    // all four BiGRU scans (doc/query x fwd/bwd), batch split in halves of 16
    k_gru5<<<8, 512, 0, stream>>>(gxd_f, gxd_b, gxq_f, gxq_b, wprep,
                                  b_hh_f, b_hh_b, docs_len, querys_len, dosb, qosb);

    // attention-over-attention
    k_mgemm<<<dim3(DLEN / 64, BATCH), 256, 0, stream>>>(dosb, qosb, Mbuf);
    k_avgbeta<<<BATCH, 256, 0, stream>>>(Mbuf, doc_mask, query_mask, docs_len, avgb);
    k_colstats<<<BATCH, 256, 0, stream>>>(Mbuf, doc_mask, mxb, csb);
    k_s<<<dim3(DLEN / 256, BATCH), 256, 0, stream>>>(Mbuf, mxb, csb, avgb, query_mask, doc_mask, sbuf);
    k_final<<<BATCH, 256, 0, stream>>>(sbuf, docs_input, candidates, answers, (float*)d_out);
}

// Round 7
// 2940.569 us; speedup vs baseline: 1.5194x; 1.0035x over previous
//
#include <hip/hip_runtime.h>
#include <hip/hip_bf16.h>
#include <math.h>

// AoA Reader v5: v4 + forced register residency of weight fragments (KEEP inline-asm
// defeats rematerialization of loop-invariant global loads).
// V=50000 E=384 H=256 B=32 D=1024 Q=64 C=10.
#define BATCH 32
#define DLEN 1024
#define QLEN 64
#define EMB 384
#define HID 256
#define G3 768   // 3*H
#define NCAND 10

typedef __attribute__((ext_vector_type(8))) short bf16x8;
typedef __attribute__((ext_vector_type(4))) float f32x4;
#define MFMA16 __builtin_amdgcn_mfma_f32_16x16x32_bf16
#define KEEP(x) asm volatile("" : "+v"(x))

__device__ __forceinline__ float bf2f(ushort u) {
    union { float f; unsigned v; } x; x.v = ((unsigned)u) << 16; return x.f;
}
__device__ __forceinline__ ushort f2bf(float f) {
    union { float f; unsigned v; } x; x.f = f;
    unsigned r = x.v + 0x7FFF + ((x.v >> 16) & 1);
    return (ushort)(r >> 16);
}
__device__ __forceinline__ float sigf(float x) {
    return __builtin_amdgcn_rcpf(1.f + __expf(-x));
}
__device__ __forceinline__ float tanhf_(float x) {
    return 1.f - 2.f * __builtin_amdgcn_rcpf(1.f + __expf(2.f * x));
}

// ---------------- prep: w_hh (768x256 f32) -> bf16 MFMA B-fragment order ----------------
// layout: [dir][wave(8)][tile(6)][ks(8)][lane(64)][e(8)] bf16; per dir 196608 elems.
__global__ __launch_bounds__(256) void k_prep(const float* __restrict__ whf, const float* __restrict__ whb,
                                              ushort* __restrict__ wprep) {
    int idx = blockIdx.x * 256 + threadIdx.x;   // < 393216
    int dir = idx / 196608;
    int r = idx - dir * 196608;
    int wv = r / 24576;  int r2 = r - wv * 24576;
    int tile = r2 / 4096; int r3 = r2 - tile * 4096;
    int ks = r3 / 512;    int r4 = r3 - ks * 512;
    int lane = r4 >> 3;   int e = r4 & 7;
    int g = (tile >> 1) * 256 + wv * 32 + (tile & 1) * 16 + (lane & 15);
    int k = ks * 32 + (lane >> 4) * 8 + e;
    const float* w = dir ? whb : whf;
    wprep[idx] = f2bf(w[g * 256 + k]);
}

// ---------------- gx GEMM with gather (fp32 compute, bf16 out) ----------------
__global__ __launch_bounds__(256) void k_gx(const int* __restrict__ tokens,
                                            const float* __restrict__ emb,
                                            const float* __restrict__ w0, const float* __restrict__ bias0, ushort* __restrict__ out0,
                                            const float* __restrict__ w1, const float* __restrict__ bias1, ushort* __restrict__ out1) {
    __shared__ float As[16][68];
    __shared__ float Bs[16][68];
    const float* w   = blockIdx.z ? w1 : w0;
    const float* bia = blockIdx.z ? bias1 : bias0;
    ushort* out      = blockIdx.z ? out1 : out0;
    int tid = threadIdx.x;
    int n0 = blockIdx.x * 64;
    long m0 = (long)blockIdx.y * 64;
    int ml = tid >> 2, el = (tid & 3) << 2;
    long tok = tokens[m0 + ml];
    const float* arow = emb + tok * EMB;
    const float* brow = w + (long)(n0 + ml) * EMB;
    int ty = tid >> 4, tx = tid & 15;
    float acc[4][4] = {};
    for (int kt = 0; kt < EMB; kt += 16) {
        float4 av = *(const float4*)(arow + kt + el);
        float4 bv = *(const float4*)(brow + kt + el);
        __syncthreads();
        As[el + 0][ml] = av.x; As[el + 1][ml] = av.y; As[el + 2][ml] = av.z; As[el + 3][ml] = av.w;
        Bs[el + 0][ml] = bv.x; Bs[el + 1][ml] = bv.y; Bs[el + 2][ml] = bv.z; Bs[el + 3][ml] = bv.w;
        __syncthreads();
#pragma unroll
        for (int k = 0; k < 16; ++k) {
            float4 a4 = *(const float4*)&As[k][ty << 2];
            float4 b4 = *(const float4*)&Bs[k][tx << 2];
            float a[4] = {a4.x, a4.y, a4.z, a4.w};
            float bb[4] = {b4.x, b4.y, b4.z, b4.w};
#pragma unroll
            for (int i = 0; i < 4; ++i)
#pragma unroll
                for (int j = 0; j < 4; ++j)
                    acc[i][j] = fmaf(a[i], bb[j], acc[i][j]);
        }
    }
#pragma unroll
    for (int i = 0; i < 4; ++i) {
        long m = m0 + (ty << 2) + i;
        int n = n0 + (tx << 2);
        ushort4 pk;
        pk.x = f2bf(acc[i][0] + bia[n + 0]);
        pk.y = f2bf(acc[i][1] + bia[n + 1]);
        pk.z = f2bf(acc[i][2] + bia[n + 2]);
        pk.w = f2bf(acc[i][3] + bia[n + 3]);
        *(ushort4*)(out + m * G3 + n) = pk;
    }
}

// ---------------- MFMA GRU: grid 8 = (batch-half, dir, seq). 512 thr = 8 waves. ----------------
// 4 B-tiles forced into VGPRs via KEEP (128 regs), 2 in LDS. Precomputed addressing.
__global__ __attribute__((amdgpu_flat_work_group_size(512, 512), amdgpu_waves_per_eu(2, 2)))
void k_gru5(
    const ushort* __restrict__ gxd_f, const ushort* __restrict__ gxd_b,
    const ushort* __restrict__ gxq_f, const ushort* __restrict__ gxq_b,
    const ushort* __restrict__ wprep,
    const float* __restrict__ bhh_f, const float* __restrict__ bhh_b,
    const int* __restrict__ dlens, const int* __restrict__ qlens,
    float* __restrict__ dosb, float* __restrict__ qosb)
{
    int wg = blockIdx.x;
    int bhalf = wg & 1;
    int dir = (wg >> 1) & 1;
    int seq = wg >> 2;                   // 0=doc, 1=query
    int T = seq ? QLEN : DLEN;
    const ushort* gx = seq ? (dir ? gxq_b : gxq_f) : (dir ? gxd_b : gxd_f);
    const float* bhh = dir ? bhh_b : bhh_f;
    const int* lens = seq ? qlens : dlens;
    float* outbase = (seq ? qosb : dosb) + dir * HID;   // uniform base
    int boff = bhalf * 16;

    int tid = threadIdx.x;
    int wv = tid >> 6;
    int lane = tid & 63;
    int l15 = lane & 15;
    int lhi = lane >> 4;                 // 0..3
    int jw = wv * 32;

    __shared__ ushort hbuf[2][4096];             // 16 KB bf16 h, swizzled, dbuf
    __shared__ ushort Blds[8][2][8][512];        // 128 KB: tiles 4,5 per wave

    // ---- resident weights: tiles 0..3 in VGPRs (forced), tiles 4,5 in LDS ----
    const ushort* wp = wprep + (size_t)dir * 196608;
    bf16x8 B0[8], B1[8], B2[8], B3[8];
#pragma unroll
    for (int ks = 0; ks < 8; ++ks) {
        B0[ks] = *(const bf16x8*)(wp + ((((wv * 6 + 0) * 8 + ks) * 64 + lane) * 8));
        B1[ks] = *(const bf16x8*)(wp + ((((wv * 6 + 1) * 8 + ks) * 64 + lane) * 8));
        B2[ks] = *(const bf16x8*)(wp + ((((wv * 6 + 2) * 8 + ks) * 64 + lane) * 8));
        B3[ks] = *(const bf16x8*)(wp + ((((wv * 6 + 3) * 8 + ks) * 64 + lane) * 8));
    }
#pragma unroll
    for (int ks = 0; ks < 8; ++ks) {
        KEEP(B0[ks]); KEEP(B1[ks]); KEEP(B2[ks]); KEEP(B3[ks]);
    }
#pragma unroll
    for (int tt = 0; tt < 2; ++tt)
#pragma unroll
        for (int ks = 0; ks < 8; ++ks) {
            bf16x8 t5 = *(const bf16x8*)(wp + ((((wv * 6 + 4 + tt) * 8 + ks) * 64 + lane) * 8));
            *(bf16x8*)((char*)&Blds[0][0][0][0] + wv * 16384 + tt * 8192 + ks * 1024 + lane * 16) = t5;
        }

    float bhr0 = bhh[jw + l15],            bhr1 = bhh[jw + 16 + l15];
    float bhz0 = bhh[256 + jw + l15],      bhz1 = bhh[256 + jw + 16 + l15];
    float bhn0 = bhh[512 + jw + l15],      bhn1 = bhh[512 + jw + 16 + l15];
    int len[4];
#pragma unroll
    for (int i = 0; i < 4; ++i) len[i] = lens[boff + lhi * 4 + i];
    float hp[2][4] = {};

    // ---- precomputed static addresses (t-invariant) ----
    int a_addr[8];
#pragma unroll
    for (int ks = 0; ks < 8; ++ks)
        a_addr[ks] = l15 * 512 + (((ks * 4 + lhi) ^ (l15 & 7)) * 16);
    int wofs[2][4];
#pragma unroll
    for (int p = 0; p < 2; ++p)
#pragma unroll
        for (int i = 0; i < 4; ++i) {
            int row = lhi * 4 + i, j = jw + p * 16 + l15;
            wofs[p][i] = (row * 256 + (((j >> 3) ^ (row & 7)) * 8) + (j & 7)) * 2;
        }
    int blbase = wv * 16384 + lane * 16;
    int lbg[4], lbo[4];                          // 32-bit lane base byte-offsets
#pragma unroll
    for (int i = 0; i < 4; ++i) {
        int b = boff + lhi * 4 + i;
        lbg[i] = b * T * (G3 * 2) + (jw + l15) * 2;
        lbo[i] = b * T * (512 * 4) + (jw + l15) * 4;
    }

    for (int x = tid; x < 4096; x += 512) hbuf[0][x] = 0;
    __syncthreads();

#define GSTEP(RB, WB, TT)                                                         \
    {                                                                             \
        int voffg[4], voffo[4];                                                   \
        _Pragma("unroll")                                                         \
        for (int i = 0; i < 4; ++i) {                                             \
            int p_ = (TT);                                                        \
            if (dir) p_ = ((TT) < len[i]) ? (len[i] - 1 - (TT)) : (TT);           \
            voffg[i] = lbg[i] + p_ * 1536;                                        \
            voffo[i] = lbo[i] + p_ * 2048;                                        \
        }                                                                         \
        ushort gxu[2][3][4];                                                      \
        _Pragma("unroll")                                                         \
        for (int i = 0; i < 4; ++i) {                                             \
            const ushort* g = (const ushort*)((const char*)gx + voffg[i]);        \
            gxu[0][0][i] = g[0];   gxu[1][0][i] = g[16];                          \
            gxu[0][1][i] = g[256]; gxu[1][1][i] = g[272];                         \
            gxu[0][2][i] = g[512]; gxu[1][2][i] = g[528];                         \
        }                                                                         \
        f32x4 acc0 = {0.f,0.f,0.f,0.f}, acc1 = acc0, acc2 = acc0,                 \
              acc3 = acc0, acc4 = acc0, acc5 = acc0;                              \
        _Pragma("unroll")                                                         \
        for (int ks = 0; ks < 8; ++ks) {                                          \
            bf16x8 a = *(const bf16x8*)((const char*)&hbuf[RB][0] + a_addr[ks]);  \
            acc0 = MFMA16(a, B0[ks], acc0, 0, 0, 0);                              \
            acc1 = MFMA16(a, B1[ks], acc1, 0, 0, 0);                              \
            acc2 = MFMA16(a, B2[ks], acc2, 0, 0, 0);                              \
            acc3 = MFMA16(a, B3[ks], acc3, 0, 0, 0);                              \
            bf16x8 b4 = *(const bf16x8*)((const char*)&Blds[0][0][0][0] + blbase + ks * 1024);        \
            bf16x8 b5 = *(const bf16x8*)((const char*)&Blds[0][0][0][0] + blbase + 8192 + ks * 1024); \
            acc4 = MFMA16(a, b4, acc4, 0, 0, 0);                                  \
            acc5 = MFMA16(a, b5, acc5, 0, 0, 0);                                  \
        }                                                                         \
        _Pragma("unroll")                                                         \
        for (int i = 0; i < 4; ++i) {                                             \
            float h2[2];                                                          \
            _Pragma("unroll")                                                     \
            for (int p = 0; p < 2; ++p) {                                         \
                float ar = p ? acc1[i] : acc0[i];                                 \
                float az = p ? acc3[i] : acc2[i];                                 \
                float an = p ? acc5[i] : acc4[i];                                 \
                float rx = bf2f(gxu[p][0][i]);                                    \
                float zx = bf2f(gxu[p][1][i]);                                    \
                float nx = bf2f(gxu[p][2][i]);                                    \
                float r = sigf(rx + ar + (p ? bhr1 : bhr0));                      \
                float z = sigf(zx + az + (p ? bhz1 : bhz0));                      \
                float nn = tanhf_(nx + r * (an + (p ? bhn1 : bhn0)));             \
                float h = (1.f - z) * nn + z * hp[p][i];                          \
                hp[p][i] = h;                                                     \
                h2[p] = h;                                                        \
                float* o = (float*)((char*)outbase + voffo[i]);                   \
                o[p * 16] = h;                                                    \
            }                                                                     \
            unsigned pk;                                                          \
            asm("v_cvt_pk_bf16_f32 %0, %1, %2" : "=v"(pk) : "v"(h2[0]), "v"(h2[1])); \
            *(ushort*)((char*)&hbuf[WB][0] + wofs[0][i]) = (ushort)(pk & 0xffffu); \
            *(ushort*)((char*)&hbuf[WB][0] + wofs[1][i]) = (ushort)(pk >> 16);    \
        }                                                                         \
        __syncthreads();                                                          \
    }

    for (int t = 0; t < T; t += 2) {
        GSTEP(0, 1, t)
        GSTEP(1, 0, t + 1)
    }
#undef GSTEP
}

// ---------------- M[b,d,q] = dos[b,d,:] . qos[b,q,:]  (K=512) ----------------
__global__ __launch_bounds__(256) void k_mgemm(const float* __restrict__ dos, const float* __restrict__ qos,
                                               float* __restrict__ Mm) {
    __shared__ float As[16][68];
    __shared__ float Bs[16][68];
    int tid = threadIdx.x;
    int b = blockIdx.y;
    long m0 = (long)blockIdx.x * 64;
    int ml = tid >> 2, el = (tid & 3) << 2;
    const float* arow = dos + ((long)b * DLEN + m0 + ml) * (2 * HID);
    const float* brow = qos + ((long)b * QLEN + ml) * (2 * HID);
    int ty = tid >> 4, tx = tid & 15;
    float acc[4][4] = {};
    for (int kt = 0; kt < 2 * HID; kt += 16) {
        float4 av = *(const float4*)(arow + kt + el);
        float4 bv = *(const float4*)(brow + kt + el);
        __syncthreads();
        As[el + 0][ml] = av.x; As[el + 1][ml] = av.y; As[el + 2][ml] = av.z; As[el + 3][ml] = av.w;
        Bs[el + 0][ml] = bv.x; Bs[el + 1][ml] = bv.y; Bs[el + 2][ml] = bv.z; Bs[el + 3][ml] = bv.w;
        __syncthreads();
#pragma unroll
        for (int k = 0; k < 16; ++k) {
            float4 a4 = *(const float4*)&As[k][ty << 2];
            float4 b4 = *(const float4*)&Bs[k][tx << 2];
            float a[4] = {a4.x, a4.y, a4.z, a4.w};
            float bb[4] = {b4.x, b4.y, b4.z, b4.w};
#pragma unroll
            for (int i = 0; i < 4; ++i)
#pragma unroll
                for (int j = 0; j < 4; ++j)
                    acc[i][j] = fmaf(a[i], bb[j], acc[i][j]);
        }
    }
#pragma unroll
    for (int i = 0; i < 4; ++i) {
        long m = m0 + (ty << 2) + i;
#pragma unroll
        for (int j = 0; j < 4; ++j) {
            int n = (tx << 2) + j;
            Mm[((long)b * DLEN + m) * QLEN + n] = acc[i][j];
        }
    }
}

// ---------------- avg_beta ----------------
__global__ __launch_bounds__(256) void k_avgbeta(const float* __restrict__ Mm, const float* __restrict__ dmask,
                                                 const float* __restrict__ qmask, const int* __restrict__ dlens,
                                                 float* __restrict__ avgb) {
    int b = blockIdx.x, tid = threadIdx.x;
    int lane = tid & 63, wid = tid >> 6;
    float qm = qmask[b * QLEN + lane];
    float acc = 0.f;
    for (int d = wid; d < DLEN; d += 4) {
        float x = Mm[((long)b * DLEN + d) * QLEN + lane];
        float mx = x;
#pragma unroll
        for (int o = 32; o; o >>= 1) mx = fmaxf(mx, __shfl_xor(mx, o));
        float e = expf(x - mx) * dmask[b * DLEN + d] * qm;
        float sm = e;
#pragma unroll
        for (int o = 32; o; o >>= 1) sm += __shfl_xor(sm, o);
        acc += e / (sm + 1e-12f);
    }
    __shared__ float red[4][QLEN];
    red[wid][lane] = acc;
    __syncthreads();
    if (tid < QLEN) {
        float tot = red[0][tid] + red[1][tid] + red[2][tid] + red[3][tid];
        avgb[b * QLEN + tid] = tot / (float)dlens[b];
    }
}

// ---------------- column stats over d ----------------
__global__ __launch_bounds__(256) void k_colstats(const float* __restrict__ Mm, const float* __restrict__ dmask,
                                                  float* __restrict__ mx, float* __restrict__ cs) {
    int b = blockIdx.x, tid = threadIdx.x;
    int q = tid & 63, dg = tid >> 6;
    float m = -INFINITY, ssum = 0.f;
    for (int d = dg; d < DLEN; d += 4) {
        float x = Mm[((long)b * DLEN + d) * QLEN + q];
        float dm = dmask[b * DLEN + d];
        float mn = fmaxf(m, x);
        ssum = ssum * expf(m - mn) + expf(x - mn) * dm;
        m = mn;
    }
    __shared__ float mS[4][QLEN], sS[4][QLEN];
    mS[dg][q] = m; sS[dg][q] = ssum;
    __syncthreads();
    if (tid < QLEN) {
        float M0 = fmaxf(fmaxf(mS[0][tid], mS[1][tid]), fmaxf(mS[2][tid], mS[3][tid]));
        float S = 0.f;
#pragma unroll
        for (int i = 0; i < 4; ++i) S += sS[i][tid] * expf(mS[i][tid] - M0);
        mx[b * QLEN + tid] = M0;
        cs[b * QLEN + tid] = S;
    }
}

// ---------------- s[b,d] ----------------
__global__ __launch_bounds__(256) void k_s(const float* __restrict__ Mm, const float* __restrict__ mxv, const float* __restrict__ cs,
                                           const float* __restrict__ avgb, const float* __restrict__ qmask, const float* __restrict__ dmask,
                                           float* __restrict__ s) {
    int b = blockIdx.y, tid = threadIdx.x;
    __shared__ float wq[QLEN], mxs[QLEN];
    if (tid < QLEN) {
        float part = cs[b * QLEN + tid];
        wq[tid] = (qmask[b * QLEN + tid] > 0.f) ? (avgb[b * QLEN + tid] / (part + 1e-12f)) : 0.f;
        mxs[tid] = mxv[b * QLEN + tid];
    }
    __syncthreads();
    long d = (long)blockIdx.x * 256 + tid;
    const float* row = Mm + ((long)b * DLEN + d) * QLEN;
    float acc = 0.f;
#pragma unroll
    for (int q = 0; q < QLEN; q += 4) {
        float4 v = *(const float4*)(row + q);
        acc += expf(v.x - mxs[q + 0]) * wq[q + 0];
        acc += expf(v.y - mxs[q + 1]) * wq[q + 1];
        acc += expf(v.z - mxs[q + 2]) * wq[q + 2];
        acc += expf(v.w - mxs[q + 3]) * wq[q + 3];
    }
    s[b * DLEN + d] = dmask[b * DLEN + d] * acc;
}

// ---------------- final ----------------
__global__ __launch_bounds__(256) void k_final(const float* __restrict__ s, const int* __restrict__ doc,
                                               const int* __restrict__ cand, const int* __restrict__ ans,
                                               float* __restrict__ out) {
    int b = blockIdx.x, tid = threadIdx.x;
    __shared__ int lc[NCAND];
    __shared__ int la;
    __shared__ float red[4][NCAND + 1];
    if (tid < NCAND) lc[tid] = cand[b * NCAND + tid];
    if (tid == NCAND) la = ans[b];
    __syncthreads();
    float accs[NCAND + 1] = {};
    for (int d = tid; d < DLEN; d += 256) {
        int tk = doc[b * DLEN + d];
        float sv = s[b * DLEN + d];
#pragma unroll
        for (int c = 0; c < NCAND; ++c)
            if (tk == lc[c]) accs[c] += sv;
        if (tk == la) accs[NCAND] += sv;
    }
    int lane = tid & 63, wid = tid >> 6;
#pragma unroll
    for (int i = 0; i <= NCAND; ++i) {
        float v = accs[i];
#pragma unroll
        for (int o = 32; o; o >>= 1) v += __shfl_xor(v, o);
        if (lane == 0) red[wid][i] = v;
    }
    __syncthreads();
    if (tid == 0) {
        float cp[NCAND + 1];
#pragma unroll
        for (int i = 0; i <= NCAND; ++i) cp[i] = red[0][i] + red[1][i] + red[2][i] + red[3][i];
        int loc = 0; float best = cp[0];
#pragma unroll
        for (int c = 1; c < NCAND; ++c) if (cp[c] > best) { best = cp[c]; loc = c; }
        out[b] = (float)lc[loc];
        out[BATCH + b] = (float)loc;
        out[2 * BATCH + b] = cp[NCAND];
    }
}

__global__ void k_zero_out(float* out, int n) {
    int i = blockIdx.x * 256 + threadIdx.x;
    if (i < n) out[i] = 0.f;
}

extern "C" void kernel_launch(void* const* d_in, const int* in_sizes, int n_in,
                              void* d_out, int out_size, void* d_ws, size_t ws_size,
                              hipStream_t stream) {
    const int*   docs_input   = (const int*)d_in[0];
    const int*   docs_len     = (const int*)d_in[1];
    const float* doc_mask     = (const float*)d_in[2];
    const int*   querys_input = (const int*)d_in[3];
    const int*   querys_len   = (const int*)d_in[4];
    const float* query_mask   = (const float*)d_in[5];
    const int*   candidates   = (const int*)d_in[6];
    const int*   answers      = (const int*)d_in[7];
    const float* embedding    = (const float*)d_in[8];
    const float* w_ih_f = (const float*)d_in[9];
    const float* w_hh_f = (const float*)d_in[10];
    const float* b_ih_f = (const float*)d_in[11];
    const float* b_hh_f = (const float*)d_in[12];
    const float* w_ih_b = (const float*)d_in[13];
    const float* w_hh_b = (const float*)d_in[14];
    const float* b_ih_b = (const float*)d_in[15];
    const float* b_hh_b = (const float*)d_in[16];

    char* ws = (char*)d_ws;
    size_t off = 0;
    auto alloc = [&](size_t bytes) { size_t o = off; off = (off + bytes + 255) & ~(size_t)255; return o; };
    ushort* wprep = (ushort*)(ws + alloc((size_t)2 * 196608 * 2));
    ushort* gxq_f = (ushort*)(ws + alloc((size_t)BATCH * QLEN * G3 * 2));
    ushort* gxq_b = (ushort*)(ws + alloc((size_t)BATCH * QLEN * G3 * 2));
    ushort* gxd_f = (ushort*)(ws + alloc((size_t)BATCH * DLEN * G3 * 2));
    ushort* gxd_b = (ushort*)(ws + alloc((size_t)BATCH * DLEN * G3 * 2));
    float* dosb  = (float*)(ws + alloc((size_t)BATCH * DLEN * 2 * HID * 4));
    float* qosb  = (float*)(ws + alloc((size_t)BATCH * QLEN * 2 * HID * 4));
    float* Mbuf  = (float*)(ws + alloc((size_t)BATCH * DLEN * QLEN * 4));
    float* avgb  = (float*)(ws + alloc((size_t)BATCH * QLEN * 4));
    float* mxb   = (float*)(ws + alloc((size_t)BATCH * QLEN * 4));
    float* csb   = (float*)(ws + alloc((size_t)BATCH * QLEN * 4));
    float* sbuf  = (float*)(ws + alloc((size_t)BATCH * DLEN * 4));

    if (ws_size < off) {
        k_zero_out<<<1, 256, 0, stream>>>((float*)d_out, out_size);
        return;
    }

    // weight fragments (bf16, MFMA B layout)
    k_prep<<<1536, 256, 0, stream>>>(w_hh_f, w_hh_b, wprep);

    // gx for queries and docs, both directions (bf16 out)
    k_gx<<<dim3(12, (BATCH * QLEN) / 64, 2), 256, 0, stream>>>(querys_input, embedding,
        w_ih_f, b_ih_f, gxq_f, w_ih_b, b_ih_b, gxq_b);
    k_gx<<<dim3(12, (BATCH * DLEN) / 64, 2), 256, 0, stream>>>(docs_input, embedding,
        w_ih_f, b_ih_f, gxd_f, w_ih_b, b_ih_b, gxd_b);

    // all four BiGRU scans (doc/query x fwd/bwd), batch split in halves of 16
    k_gru5<<<8, 512, 0, stream>>>(gxd_f, gxd_b, gxq_f, gxq_b, wprep,
                                  b_hh_f, b_hh_b, docs_len, querys_len, dosb, qosb);

    // attention-over-attention
    k_mgemm<<<dim3(DLEN / 64, BATCH), 256, 0, stream>>>(dosb, qosb, Mbuf);
    k_avgbeta<<<BATCH, 256, 0, stream>>>(Mbuf, doc_mask, query_mask, docs_len, avgb);
    k_colstats<<<BATCH, 256, 0, stream>>>(Mbuf, doc_mask, mxb, csb);
    k_s<<<dim3(DLEN / 256, BATCH), 256, 0, stream>>>(Mbuf, mxb, csb, avgb, query_mask, doc_mask, sbuf);
    k_final<<<BATCH, 256, 0, stream>>>(sbuf, docs_input, candidates, answers, (float*)d_out);
}